// Round 13
// baseline (2258.651 us; speedup 1.0000x reference)
//
#include <hip/hip_runtime.h>

typedef short bf16x8 __attribute__((ext_vector_type(8)));   // 8 bf16 in 4 VGPRs
typedef float f32x4  __attribute__((ext_vector_type(4)));
typedef int   i32x4  __attribute__((ext_vector_type(4)));

#define DEVINL __device__ __forceinline__

// ---------------------------------------------------------------------------
// Problem: B=256, T=128, V=10000, E=256, U=1024, 4U=4096, O=1024
// fixed ws ~45 MB + tc*5.25 MB
// ---------------------------------------------------------------------------
static constexpr size_t SZ_WIM  = 4096ull * 512 * 2;   // W img  [4096][hi256|lo256]
static constexpr size_t SZ_FCW  = 1024ull * 2048 * 2;  // fc img [1024][hi1024|lo1024]
static constexpr size_t SZ_UIM  = 8388608;             // U i8 frag img, 2 planes
static constexpr size_t SZ_EBI  = 10000ull * 512 * 2;  // emb img [10000][hi256|lo256]
static constexpr size_t SZ_HH   = 33ull * 524288;      // h history [33 slot][256][1024] u16
static constexpr size_t SZ_CB   = 1048576;             // c state [256][1024] f32
static constexpr size_t SZ_LEN  = 4096;
static constexpr size_t SZ_DIAG = 2048;                // prog[0..15] + flags at +256B

DEVINL unsigned short bf16rn(float x){
  unsigned u = __float_as_uint(x);
  unsigned r = (u + 0x7fffu + ((u >> 16) & 1u)) >> 16;
  return (unsigned short)r;
}
DEVINL unsigned short bf16lo(float x){
  unsigned ub = __float_as_uint(x);
  return bf16rn(x - __uint_as_float(ub & 0xffff0000u));
}
DEVINL float sigm(float x){ return 1.f / (1.f + __expf(-x)); }
DEVINL float tanhfast(float x){
  float xc = fminf(15.f, fmaxf(-15.f, x));
  float e = __expf(2.f * xc);
  return (e - 1.f) / (e + 1.f);
}
// async 16B global->LDS DMA; LDS dest = wave-uniform base + lane*16,
// global source is PER-LANE (gather/pre-swizzle legal).  size must be literal.
DEVINL void gl_lds16(const void* g, void* l){
  __builtin_amdgcn_global_load_lds(
      (const __attribute__((address_space(1))) unsigned*)g,
      (__attribute__((address_space(3))) unsigned*)l, 16, 0, 0);
}
DEVINL int hslot(int t){ return t % 33; }   // 33 slots: distinct within a launch

// ---------------------------------------------------------------------------
__global__ void __launch_bounds__(256) probe_fill(float* __restrict__ out, int n, float v)
{
  int i = blockIdx.x * 256 + threadIdx.x;
  if (i < n) out[i] = (i == 0) ? v : 0.f;
}

// diag: if a stage marker is missing, flood out[0..1023] with 100+stage
__global__ void __launch_bounds__(64) diag_check(const int* __restrict__ prog,
                                                 float* __restrict__ out)
{
  if (threadIdx.x == 0){
    int miss = 0;
    for (int i = 7; i >= 1; i--) if (prog[i] == 0) miss = i;
    if (miss){
      for (int k = 0; k < 1024; k++) out[k] = 100.0f + (float)miss;
    }
  }
}

// ---------------------------------------------------------------------------
__global__ void __launch_bounds__(128) len_kernel(const int* __restrict__ seq,
                                                  int* __restrict__ len,
                                                  int* __restrict__ prog)
{
  int b = blockIdx.x, t = threadIdx.x;
  if (b == 0 && t == 0) prog[1] = 1;
  int pred = (seq[b * 128 + t] != 0) ? 1 : 0;
  unsigned long long m = __ballot(pred);
  __shared__ int cnt[2];
  if ((t & 63) == 0) cnt[t >> 6] = __popcll(m);
  __syncthreads();
  if (t == 0) len[b] = cnt[0] + cnt[1];
}

// ---------------------------------------------------------------------------
// transpose f32 [Ksrc][N] -> bf16 image [N][2*Ksrc] = [hi | lo]
// ---------------------------------------------------------------------------
__global__ void __launch_bounds__(256) prep_split_img(
    const float* __restrict__ S, unsigned short* __restrict__ img, int N, int Ksrc,
    int* __restrict__ prog, int stage)
{
  __shared__ float tile[64][65];
  const int nt = N >> 6;
  const int bn = blockIdx.x % nt, bk = blockIdx.x / nt;
  const int tid = threadIdx.x;
  if (blockIdx.x == 0 && tid == 0) prog[stage] = 1;
  {
    const int kk = tid >> 6, n = tid & 63;
#pragma unroll 4
    for (int i = 0; i < 16; i++){
      int k = i * 4 + kk;
      tile[k][n] = S[(size_t)((bk << 6) + k) * N + (bn << 6) + n];
    }
  }
  __syncthreads();
  {
    const int n4 = tid >> 6, k = tid & 63;
#pragma unroll 4
    for (int i = 0; i < 16; i++){
      int n = i * 4 + n4;
      float v = tile[k][n];
      size_t rowoff = (size_t)((bn << 6) + n) * (2 * Ksrc) + (bk << 6) + k;
      img[rowoff] = (unsigned short)(__float_as_uint(v) >> 16);
      img[rowoff + Ksrc] = bf16lo(v);
    }
  }
}

// ---------------------------------------------------------------------------
// emb f32 [10000][256] -> u16 image [10000][hi256|lo256]
// ---------------------------------------------------------------------------
__global__ void __launch_bounds__(256) prep_emb_img(const float* __restrict__ emb,
                                                    unsigned short* __restrict__ img)
{
  const int v = blockIdx.x, t = threadIdx.x;
  float x = emb[(size_t)v * 256 + t];
  img[(size_t)v * 512 + t]       = (unsigned short)(__float_as_uint(x) >> 16);
  img[(size_t)v * 512 + 256 + t] = bf16lo(x);
}

// ---------------------------------------------------------------------------
// U (f32 [1024][4096]) -> i8 fragment image, 2 planes (hi,lo of 16-bit *2^17)
// ---------------------------------------------------------------------------
__global__ void __launch_bounds__(256) prep_uimg(const float* __restrict__ U,
                                                 signed char* __restrict__ img,
                                                 int* __restrict__ prog)
{
  const int bid = blockIdx.x;
  const int nb = bid >> 2, nt4 = bid & 3;
  const int tid = threadIdx.x;
  if (bid == 0 && tid == 0) prog[4] = 1;
  __shared__ signed char lc[16384], ldq[16384];  // [k 1024][16 cols]
  const int colbase = nt4 * 1024 + (nb << 4);
  const int kk = tid >> 4, cc = tid & 15;
#pragma unroll 4
  for (int it = 0; it < 64; it++){
    int k = it * 16 + kk;
    float v = U[(size_t)k * 4096 + colbase + cc];
    int q = (int)rintf(v * 131072.f);            // U * 2^17
    q = q > 32639 ? 32639 : (q < -32639 ? -32639 : q);
    int a = (q + 128) >> 8;
    int d = q - (a << 8);
    lc[(k << 4) + cc]  = (signed char)a;
    ldq[(k << 4) + cc] = (signed char)d;
  }
  __syncthreads();
#pragma unroll
  for (int rep = 0; rep < 4; rep++){
    int idx = rep * 256 + tid;                   // 0..1023
    int kt = idx >> 6, lane = idx & 63;
    int n = lane & 15, quad = lane >> 4;
    union { signed char b[16]; i32x4 v; } cb_, db_;
#pragma unroll
    for (int j = 0; j < 16; j++){
      int k = (kt << 6) + (quad << 4) + j;
      cb_.b[j] = lc[(k << 4) + n];
      db_.b[j] = ldq[(k << 4) + n];
    }
    size_t base = (size_t)((((nb << 2) + nt4) * 16 + kt) * 2) * 1024;
    *(i32x4*)(img + base + (size_t)lane * 16)        = cb_.v;
    *(i32x4*)(img + base + 1024 + (size_t)lane * 16) = db_.v;
  }
}

// ---------------------------------------------------------------------------
// gates GEMM: xg[256*tc][4096] = token-gathered ebimg x Wimg + bias (3-product).
// Double-buffered DMA pipeline (R12; correctness-proven, perf-neutral).
// ---------------------------------------------------------------------------
__global__ void __launch_bounds__(256) gemm_gates(
    const unsigned short* __restrict__ Aimg, const unsigned short* __restrict__ Bimg,
    const float* __restrict__ bias, float* __restrict__ D,
    const int* __restrict__ seq, int c0, int tcsh, int* __restrict__ prog)
{
  __shared__ __align__(16) char lds[32768];
  __shared__ int stok[128];
  const int tid = threadIdx.x, lane = tid & 63, wv = tid >> 6;
  const int quad = lane >> 4, nlo = lane & 15;
  const int wm = wv & 1, wn = wv >> 1;
  const int rowbase = (blockIdx.x >> 5) << 7;   // 32 col-tiles
  const int colbase = (blockIdx.x & 31) << 7;
  const int tcm1 = (1 << tcsh) - 1;
  if (blockIdx.x == 0 && tid == 0) prog[5] = 1;
  if (tid < 128){
    int r = rowbase + tid;
    stok[tid] = seq[((r >> tcsh) << 7) + c0 + (r & tcm1)];
  }
  __syncthreads();

  f32x4 acc[4][4];
#pragma unroll
  for (int i = 0; i < 4; i++)
#pragma unroll
    for (int j = 0; j < 4; j++) acc[i][j] = (f32x4){0.f, 0.f, 0.f, 0.f};

  const unsigned short* asrc[2]; const unsigned short* bsrc[2];
  char* adst[2]; char* bdst[2];
#pragma unroll
  for (int p = 0; p < 2; p++){
    int gidx = p * 256 + tid;
    int row = gidx >> 2, sg = gidx & 3;
    int sgs = sg ^ ((row >> 1) & 3);
    asrc[p] = Aimg + (size_t)stok[row] * 512 + sgs * 8;
    bsrc[p] = Bimg + (size_t)(colbase + row) * 512 + sgs * 8;
    adst[p] = &lds[p * 4096 + wv * 1024];
    bdst[p] = &lds[16384 + p * 4096 + wv * 1024];
  }

  auto stage = [&](int c, int cur){
    int k0 = c * 32;
    int seg = (k0 >= 512) ? 2 : (k0 >= 256 ? 1 : 0);
    int acol = k0 - seg * 256;
    int aoff = (seg == 1 ? 256 : 0) + acol;
    int boff = (seg == 2 ? 256 : 0) + acol;
#pragma unroll
    for (int p = 0; p < 2; p++){
      gl_lds16(asrc[p] + aoff, adst[p] + cur * 8192);
      gl_lds16(bsrc[p] + boff, bdst[p] + cur * 8192);
    }
  };

  stage(0, 0);
  int cur = 0;
#pragma unroll 2
  for (int c = 0; c < 24; c++){
    __syncthreads();                     // buf[cur] DMA complete on all waves
    if (c + 1 < 24) stage(c + 1, cur ^ 1);
    bf16x8 af[4], bfr[4];
#pragma unroll
    for (int mt = 0; mt < 4; mt++){
      int r = wm * 64 + mt * 16 + nlo;
      af[mt] = *(const bf16x8*)(&lds[cur * 8192 + r * 64 + ((quad ^ ((r >> 1) & 3)) << 4)]);
    }
#pragma unroll
    for (int nt = 0; nt < 4; nt++){
      int r = wn * 64 + nt * 16 + nlo;
      bfr[nt] = *(const bf16x8*)(&lds[16384 + cur * 8192 + r * 64 + ((quad ^ ((r >> 1) & 3)) << 4)]);
    }
#pragma unroll
    for (int mt = 0; mt < 4; mt++)
#pragma unroll
      for (int nt = 0; nt < 4; nt++)
        acc[mt][nt] = __builtin_amdgcn_mfma_f32_16x16x32_bf16(af[mt], bfr[nt], acc[mt][nt], 0, 0, 0);
    cur ^= 1;
  }

  float bs[4];
#pragma unroll
  for (int nt = 0; nt < 4; nt++) bs[nt] = bias[colbase + wn * 64 + nt * 16 + nlo];
#pragma unroll
  for (int mt = 0; mt < 4; mt++)
#pragma unroll
    for (int nt = 0; nt < 4; nt++){
      int col = colbase + wn * 64 + nt * 16 + nlo;
#pragma unroll
      for (int r = 0; r < 4; r++){
        int row = rowbase + wm * 64 + mt * 16 + quad * 4 + r;
        D[(size_t)row * 4096 + col] = acc[mt][nt][r] + bs[nt];
      }
    }
}

// ---------------------------------------------------------------------------
// output GEMM: out[b*128+c0+s][1024] = ohol x fcw + fcb (3-product, K'=3072)
// Double-buffered DMA pipeline (R12).
// ---------------------------------------------------------------------------
__global__ void __launch_bounds__(256) gemm_out(
    const unsigned short* __restrict__ ohol, const unsigned short* __restrict__ Bimg,
    const float* __restrict__ bias, float* __restrict__ D,
    int c0, int tcsh, int* __restrict__ prog)
{
  __shared__ __align__(16) char lds[32768];
  const int tid = threadIdx.x, lane = tid & 63, wv = tid >> 6;
  const int quad = lane >> 4, nlo = lane & 15;
  const int wm = wv & 1, wn = wv >> 1;
  const int rowbase = (blockIdx.x >> 3) << 7;   // 8 col-tiles
  const int colbase = (blockIdx.x & 7) << 7;
  const int tcm1 = (1 << tcsh) - 1;
  if (blockIdx.x == 0 && tid == 0) prog[7] = 1;

  f32x4 acc[4][4];
#pragma unroll
  for (int i = 0; i < 4; i++)
#pragma unroll
    for (int j = 0; j < 4; j++) acc[i][j] = (f32x4){0.f, 0.f, 0.f, 0.f};

  const unsigned short* asrc[2]; const unsigned short* bsrc[2];
  char* adst[2]; char* bdst[2];
#pragma unroll
  for (int p = 0; p < 2; p++){
    int gidx = p * 256 + tid;
    int row = gidx >> 2, sg = gidx & 3;
    int sgs = sg ^ ((row >> 1) & 3);
    asrc[p] = ohol + (size_t)(rowbase + row) * 2048 + sgs * 8;
    bsrc[p] = Bimg + (size_t)(colbase + row) * 2048 + sgs * 8;
    adst[p] = &lds[p * 4096 + wv * 1024];
    bdst[p] = &lds[16384 + p * 4096 + wv * 1024];
  }

  auto stage = [&](int c, int cur){
    int k0 = c * 32;
    int seg = (k0 >= 2048) ? 2 : (k0 >= 1024 ? 1 : 0);
    int acol = k0 - seg * 1024;
    int aoff = (seg == 1 ? 1024 : 0) + acol;
    int boff = (seg == 2 ? 1024 : 0) + acol;
#pragma unroll
    for (int p = 0; p < 2; p++){
      gl_lds16(asrc[p] + aoff, adst[p] + cur * 8192);
      gl_lds16(bsrc[p] + boff, bdst[p] + cur * 8192);
    }
  };

  stage(0, 0);
  int cur = 0;
#pragma unroll 2
  for (int c = 0; c < 96; c++){
    __syncthreads();                     // buf[cur] DMA complete on all waves
    if (c + 1 < 96) stage(c + 1, cur ^ 1);
    bf16x8 af[4], bfr[4];
#pragma unroll
    for (int mt = 0; mt < 4; mt++){
      int r = wm * 64 + mt * 16 + nlo;
      af[mt] = *(const bf16x8*)(&lds[cur * 8192 + r * 64 + ((quad ^ ((r >> 1) & 3)) << 4)]);
    }
#pragma unroll
    for (int nt = 0; nt < 4; nt++){
      int r = wn * 64 + nt * 16 + nlo;
      bfr[nt] = *(const bf16x8*)(&lds[16384 + cur * 8192 + r * 64 + ((quad ^ ((r >> 1) & 3)) << 4)]);
    }
#pragma unroll
    for (int mt = 0; mt < 4; mt++)
#pragma unroll
      for (int nt = 0; nt < 4; nt++)
        acc[mt][nt] = __builtin_amdgcn_mfma_f32_16x16x32_bf16(af[mt], bfr[nt], acc[mt][nt], 0, 0, 0);
    cur ^= 1;
  }

  float bs[4];
#pragma unroll
  for (int nt = 0; nt < 4; nt++) bs[nt] = bias[colbase + wn * 64 + nt * 16 + nlo];
#pragma unroll
  for (int mt = 0; mt < 4; mt++)
#pragma unroll
    for (int nt = 0; nt < 4; nt++){
      int col = colbase + wn * 64 + nt * 16 + nlo;
#pragma unroll
      for (int r = 0; r < 4; r++){
        int row = rowbase + wm * 64 + mt * 16 + quad * 4 + r;
        int drow = ((row >> tcsh) << 7) + c0 + (row & tcm1);
        D[(size_t)drow * 1024 + col] = acc[mt][nt][r] + bs[nt];
      }
    }
}

// ---------------------------------------------------------------------------
// DATAFLOW sync (R13): per-chunk producer flags replace the 64-WG lockstep
// barrier.  h chunk c (u16 cols [128c,128c+128)) is produced by WGs
// nb in [8c, 8c+8).  Reader of h(t) chunk c waits for those 8 flags >= t,
// checked right before staging that chunk -> the wait overlaps MFMA on
// earlier chunks, and per-step convergence of all 64 WGs is never required.
// Ordering (R9-proven): producer's returning-xchg h-stores are AT the MALL
// when its __syncthreads' vmcnt(0) passes; flag store (relaxed agent, sc1)
// follows.  Reader: relaxed atomic polls + compiler-only acquire fence (no
// cache ops; blocks speculative hoisting of the subsequent h loads).  h
// addresses are launch-fresh (hh slots) -> plain cached loads, no invalidate.
// Deadlock-free: dependency graph is forward-only in (t, chunk); the
// minimum-step WG's producers have all finished step t_min-1.
// ---------------------------------------------------------------------------
DEVINL void wait_chunk(int* flags, int c, int tgt, int lane){
  int f = (c << 3) + (lane & 7);
  for (;;){
    int v = __hip_atomic_load(&flags[f], __ATOMIC_RELAXED, __HIP_MEMORY_SCOPE_AGENT);
    if (__ballot(v >= tgt) == ~0ull) break;
    __builtin_amdgcn_s_sleep(1);
  }
  __builtin_amdgcn_fence(__ATOMIC_ACQUIRE, "workgroup");  // compiler ordering only
}

// ---------------------------------------------------------------------------
// persistent LSTM recurrence, tc steps/launch.  256 WGs x 512 thr = 4 mb x 64 nb.
// R13: R10-proven body with the end-of-step mbbar replaced by the per-chunk
// dataflow flags above (writer: one relaxed flag store after the vmcnt-drain
// sync; reader: wait_chunk before each chunk's staging loads).
// ---------------------------------------------------------------------------
__global__ void __launch_bounds__(512, 2) lstm_rec(
    const float* __restrict__ xg,        // [256*tc][4096] f32, row = b*tc+s
    const signed char* __restrict__ uimg,
    const int* __restrict__ len,
    signed char* __restrict__ hh,        // [33 slot][256][1024] u16 packed history
    float* __restrict__ cbuf,            // [256][1024] f32
    unsigned short* __restrict__ ohol,   // [256*tc][hi1024|lo1024]
    int* __restrict__ barbase,           // flags[mb] at barbase + mb*64 ints
    int* __restrict__ prog,
    int c0, int tcsh)
{
  // LDS: [0,16384) h tile (2 pl x 64 r x 128B, 16B-granule XOR swizzle);
  //      [16384,32768) xg f32 [64][64]; [32768,50176) z f32 [64][68]
  __shared__ __align__(16) char lds[50176];
  const int tc = 1 << tcsh;
  const int wg = blockIdx.x, mb = wg >> 6, nb = wg & 63;
  const int tid = threadIdx.x, lane = tid & 63, wv = tid >> 6;  // wv 0..7
  const int quad = lane >> 4, nlo = lane & 15;
  const int mh = wv & 1, g = wv >> 1;                           // gate 0..3
  int* flags = barbase + (mb << 6);
  if (wg == 0 && tid == 0) prog[6] = 1;

  const unsigned short* hh2 = (const unsigned short*)hh;

  // ---- U fragments -> registers: gate g, u-block nb, 16 kt x 2 planes ----
  i32x4 Bf[16][2];
#pragma unroll
  for (int kt = 0; kt < 16; kt++)
#pragma unroll
    for (int pl = 0; pl < 2; pl++){
      size_t off = (size_t)((((nb << 2) + g) * 16 + kt) * 2 + pl);
      off = (off * 64 + lane) << 4;
      Bf[kt][pl] = *(const i32x4*)(uimg + off);
    }

  // ---- elementwise mapping: thread = (1 row x 2 adjacent cols) ----
  const int erow = tid >> 3;            // 0..63 local row
  const int ecp  = tid & 7;             // col-pair index
  const int ecol0 = ecp << 1;           // local col (even)
  const int ucol0 = (nb << 4) + ecol0;  // global u col (even)
  const int bglob = (mb << 6) + erow;
  const int lenr = len[bglob];
  float cst[2], hst[2];
#pragma unroll
  for (int r = 0; r < 2; r++){
    cst[r] = cbuf[(size_t)bglob * 1024 + ucol0 + r];
    unsigned short e = hh2[(size_t)hslot(c0) * 262144 + (size_t)bglob * 1024 + ucol0 + r];
    int a = (signed char)(e >> 8), b_ = (signed char)(e & 255);
    hst[r] = (float)(a * 256 + b_) * (1.0f / 32512.0f);
  }

  // xg prefetch: issued early so HBM latency hides under the flag waits.
  float4 xreg[2];
  auto load_x = [&](int s){
#pragma unroll
    for (int it = 0; it < 2; it++){
      int idx = it * 512 + tid;
      int row = idx >> 4, c4 = idx & 15;
      xreg[it] = *(const float4*)(xg + (size_t)((((mb << 6) + row) << tcsh) + s) * 4096
                                  + (c4 >> 2) * 1024 + (nb << 4) + ((c4 & 3) << 2));
    }
  };
  load_x(0);

  // h staging mapping: thread = (1 row x one 32B packed block of 8)
  const int hrw = tid >> 3, hsub = tid & 7;

#pragma unroll 1
  for (int s = 0; s < tc; s++){
    const int t = c0 + s;
    // input h of step t lives at slot hslot(t) (launch-fresh -> plain loads)
    const signed char* hsrc = hh + (size_t)hslot(t) * 524288 + (size_t)(mb << 6) * 2048;

    i32x4 accH[2], accM[2], accL[2];
#pragma unroll
    for (int m = 0; m < 2; m++){
      accH[m] = (i32x4){0,0,0,0};
      accM[m] = (i32x4){0,0,0,0};
      accL[m] = (i32x4){0,0,0,0};
    }

    int4 hregA[2], hregB[2];
    auto load_hto = [&](int c, int4* dst){
      const signed char* p = hsrc + (size_t)hrw * 2048 + c * 256 + hsub * 32;
      dst[0] = *(const int4*)p;
      dst[1] = *(const int4*)(p + 16);
    };
    // split packed u16 block (16 cols) -> hi plane 16B + lo plane 16B, write
    // with the R5 16B-granule swizzle (low bank-conflict layout).
    auto write_hf = [&](const int4* src){
      unsigned r0 = (unsigned)src[0].x, r1 = (unsigned)src[0].y;
      unsigned r2 = (unsigned)src[0].z, r3 = (unsigned)src[0].w;
      unsigned r4 = (unsigned)src[1].x, r5 = (unsigned)src[1].y;
      unsigned r6 = (unsigned)src[1].z, r7 = (unsigned)src[1].w;
      i32x4 lo, hi;
      lo[0] = __builtin_amdgcn_perm(r1, r0, 0x06040200u);
      lo[1] = __builtin_amdgcn_perm(r3, r2, 0x06040200u);
      lo[2] = __builtin_amdgcn_perm(r5, r4, 0x06040200u);
      lo[3] = __builtin_amdgcn_perm(r7, r6, 0x06040200u);
      hi[0] = __builtin_amdgcn_perm(r1, r0, 0x07050301u);
      hi[1] = __builtin_amdgcn_perm(r3, r2, 0x07050301u);
      hi[2] = __builtin_amdgcn_perm(r5, r4, 0x07050301u);
      hi[3] = __builtin_amdgcn_perm(r7, r6, 0x07050301u);
      int sw = (hsub ^ (hrw & 7)) << 4;
      *(i32x4*)(&lds[hrw * 128 + sw])        = hi;   // plane 0 = hi bytes (a)
      *(i32x4*)(&lds[8192 + hrw * 128 + sw]) = lo;   // plane 1 = lo bytes (b)
    };

    wait_chunk(flags, 0, t, lane);
    load_hto(0, hregA);
    wait_chunk(flags, 1, t, lane);
    load_hto(1, hregB);

#pragma unroll                         // FULL unroll: Bf[kt] compile-time
    for (int c = 0; c < 8; c++){
      __syncthreads();
      if ((c & 1) == 0) write_hf(hregA); else write_hf(hregB);
      if (c == 0){
#pragma unroll
        for (int it = 0; it < 2; it++){
          int idx = it * 512 + tid;
          int row = idx >> 4, c4 = idx & 15;
          *(float4*)(&lds[16384 + row * 256 + c4 * 16]) = xreg[it];
        }
      }
      __syncthreads();
      if (c + 2 < 8){
        wait_chunk(flags, c + 2, t, lane);    // overlaps with MFMA below
        if ((c & 1) == 0) load_hto(c + 2, hregA); else load_hto(c + 2, hregB);
      }
#pragma unroll
      for (int kt2 = 0; kt2 < 2; kt2++){
        const int kt = c * 2 + kt2;
        i32x4 Af[2][2];
#pragma unroll
        for (int m = 0; m < 2; m++){
          int hrow = (mh << 5) + (m << 4) + nlo;
          int sgl = ((kt2 << 2) + quad) ^ (hrow & 7);
          Af[m][0] = *(const i32x4*)(&lds[hrow * 128 + (sgl << 4)]);
          Af[m][1] = *(const i32x4*)(&lds[8192 + hrow * 128 + (sgl << 4)]);
        }
#pragma unroll
        for (int m = 0; m < 2; m++){
          accH[m] = __builtin_amdgcn_mfma_i32_16x16x64_i8(Af[m][0], Bf[kt][0], accH[m], 0, 0, 0);
          accM[m] = __builtin_amdgcn_mfma_i32_16x16x64_i8(Af[m][0], Bf[kt][1], accM[m], 0, 0, 0);
          accM[m] = __builtin_amdgcn_mfma_i32_16x16x64_i8(Af[m][1], Bf[kt][0], accM[m], 0, 0, 0);
          accL[m] = __builtin_amdgcn_mfma_i32_16x16x64_i8(Af[m][1], Bf[kt][1], accL[m], 0, 0, 0);
        }
      }
    }
    __syncthreads();

    // prefetch next step's xg under the z/elementwise phases
    if (s + 1 < tc) load_x(s + 1);

    // ---- z = (65536*accH + 256*accM + accL)/(32512*2^17) -> LDS ----
    const float cH = 1.0f / 65024.0f;
    const float cM = 1.0f / 16646144.0f;
    const float cL = 1.0f / 4261412864.0f;
#pragma unroll
    for (int m = 0; m < 2; m++){
#pragma unroll
      for (int r = 0; r < 4; r++){
        float z = (float)accH[m][r] * cH
                + (float)accM[m][r] * cM
                + (float)accL[m][r] * cL;
        int zrow = (mh << 5) + (m << 4) + (quad << 2) + r;
        *(float*)(&lds[32768 + (((zrow * 68) + g * 16 + nlo) << 2)]) = z;
      }
    }
    __syncthreads();

    {
      float ho16[2];
      unsigned enc2 = 0;
#pragma unroll
      for (int r = 0; r < 2; r++){
        int col = ecol0 + r;
        float zi = *(const float*)(&lds[32768 + (((erow * 68) + 0  + col) << 2)])
                 + *(const float*)(&lds[16384 + (((erow << 6) + 0  + col) << 2)]);
        float zf = *(const float*)(&lds[32768 + (((erow * 68) + 16 + col) << 2)])
                 + *(const float*)(&lds[16384 + (((erow << 6) + 16 + col) << 2)]);
        float zg = *(const float*)(&lds[32768 + (((erow * 68) + 32 + col) << 2)])
                 + *(const float*)(&lds[16384 + (((erow << 6) + 32 + col) << 2)]);
        float zo = *(const float*)(&lds[32768 + (((erow * 68) + 48 + col) << 2)])
                 + *(const float*)(&lds[16384 + (((erow << 6) + 48 + col) << 2)]);
        float iv = sigm(zi), fv = sigm(zf), ov = sigm(zo), gv = tanhfast(zg);
        float cn = fv * cst[r] + iv * gv;
        float hn = ov * tanhfast(cn);
        bool vld = (t < lenr);
        cst[r] = vld ? cn : cst[r];
        hst[r] = vld ? hn : hst[r];
        ho16[r] = vld ? hn : 0.f;
        int H = (int)rintf(hst[r] * 32512.f);
        H = H > 32512 ? 32512 : (H < -32512 ? -32512 : H);
        int a = (H + 128) >> 8;
        int b_ = H - (a << 8);
        unsigned e = (((unsigned)a & 255u) << 8) | ((unsigned)b_ & 255u);
        enc2 |= e << (r * 16);
      }
      // ohol: 2 adjacent cols -> u32 stores (hi plane, lo plane)
      size_t orow = ((size_t)bglob << tcsh) + s;
      unsigned hi2 = (unsigned)(__float_as_uint(ho16[0]) >> 16)
                   | ((unsigned)(__float_as_uint(ho16[1]) >> 16) << 16);
      unsigned lo2 = (unsigned)bf16lo(ho16[0]) | ((unsigned)bf16lo(ho16[1]) << 16);
      *(unsigned*)(ohol + orow * 2048 + ucol0)        = hi2;
      *(unsigned*)(ohol + orow * 2048 + 1024 + ucol0) = lo2;
      // h(t+1) -> FRESH slot: ONE returning 32-bit atomic exchange (provable
      // release — vmcnt retires only on MALL response).
      unsigned* hp = (unsigned*)(hh + (size_t)hslot(t + 1) * 524288
                                 + ((size_t)bglob * 1024 + ucol0) * 2);
      unsigned old = __hip_atomic_exchange(hp, enc2, __ATOMIC_RELAXED,
                                           __HIP_MEMORY_SCOPE_AGENT);
      asm volatile("" :: "v"(old));   // consume result -> returning form
    }
    // publish: all 512 threads' h-exchanges RESPONDED (vmcnt drained by the
    // barrier), then ONE relaxed flag store.  No reader-side cache ops needed.
    __syncthreads();
    if (tid == 0)
      __hip_atomic_store(&flags[nb], t + 1, __ATOMIC_RELAXED, __HIP_MEMORY_SCOPE_AGENT);
  }

#pragma unroll
  for (int r = 0; r < 2; r++)
    cbuf[(size_t)bglob * 1024 + ucol0 + r] = cst[r];
}

// ---------------------------------------------------------------------------
extern "C" void kernel_launch(void* const* d_in, const int* in_sizes, int n_in,
                              void* d_out, int out_size, void* d_ws, size_t ws_size,
                              hipStream_t stream)
{
  const int*   seq = (const int*)  d_in[0];
  const float* emb = (const float*)d_in[1];
  const float* Wm  = (const float*)d_in[2];
  const float* Um  = (const float*)d_in[3];
  const float* bv  = (const float*)d_in[4];
  const float* fcW = (const float*)d_in[5];
  const float* fcb = (const float*)d_in[6];
  float* out = (float*)d_out;
  char* ws = (char*)d_ws;

  // marker: survives iff no kernel/memset below ever touches d_out
  hipMemsetAsync(d_out, 0x42, 256, stream);   // 64 floats = 48.566

  size_t off = 0;
  unsigned short* wim = (unsigned short*)(ws + off); off += SZ_WIM;
  unsigned short* fcw = (unsigned short*)(ws + off); off += SZ_FCW;
  signed char*    uim = (signed char*)(ws + off);    off += SZ_UIM;
  unsigned short* ebi = (unsigned short*)(ws + off); off += SZ_EBI;
  signed char*    hh  = (signed char*)(ws + off);    off += SZ_HH;
  float*          cb  = (float*)(ws + off);          off += SZ_CB;
  int*            len = (int*)(ws + off);            off += SZ_LEN;
  int*            diag= (int*)(ws + off);            off += SZ_DIAG;
  const size_t fixed = off;

  int tcsh = -1;
  for (int s = 5; s >= 0; s--)
    if (ws && fixed + (5242880ull << s) <= ws_size){ tcsh = s; break; }

  if (tcsh < 0){
    probe_fill<<<(out_size + 255) / 256, 256, 0, stream>>>(
        out, out_size, 1000.0f + (float)(ws_size >> 20));
    return;
  }
  const int tc = 1 << tcsh;

  float*          xgc  = (float*)(ws + fixed);
  unsigned short* ohol = (unsigned short*)(ws + fixed + (size_t)tc * 4194304);

  hipMemsetAsync(diag, 0, SZ_DIAG, stream);   // prog + per-mb chunk flags
  hipMemsetAsync(hh, 0, 524288, stream);      // h history slot 0 = 0 (enc(0)=0)
  hipMemsetAsync(cb, 0, SZ_CB, stream);       // c state = 0

  int* prog = diag;
  int* barbase = diag + 64;                   // flags: 4 mb x 64 ints, 256B apart

  len_kernel<<<256, 128, 0, stream>>>(seq, len, prog);
  prep_split_img<<<256, 256, 0, stream>>>(Wm, wim, 4096, 256, prog, 2);
  prep_split_img<<<256, 256, 0, stream>>>(fcW, fcw, 1024, 1024, prog, 3);
  prep_emb_img<<<10000, 256, 0, stream>>>(emb, ebi);
  prep_uimg<<<256, 256, 0, stream>>>(Um, uim, prog);

  for (int c0 = 0; c0 < 128; c0 += tc){
    gemm_gates<<<dim3((2 * tc) * 32), 256, 0, stream>>>(ebi, wim, bv, xgc, seq, c0, tcsh, prog);
    lstm_rec<<<dim3(256), 512, 0, stream>>>(xgc, uim, len, hh, cb, ohol, barbase, prog, c0, tcsh);
    gemm_out<<<dim3((2 * tc) * 8), 256, 0, stream>>>(ohol, fcw, fcb, out, c0, tcsh, prog);
  }

  diag_check<<<1, 64, 0, stream>>>(prog, out);
}

// Round 14
// 1878.065 us; speedup vs baseline: 1.2026x; 1.2026x over previous
//
#include <hip/hip_runtime.h>

typedef short bf16x8 __attribute__((ext_vector_type(8)));   // 8 bf16 in 4 VGPRs
typedef float f32x4  __attribute__((ext_vector_type(4)));
typedef int   i32x4  __attribute__((ext_vector_type(4)));

#define DEVINL __device__ __forceinline__

// ---------------------------------------------------------------------------
// Problem: B=256, T=128, V=10000, E=256, U=1024, 4U=4096, O=1024
// fixed ws ~45 MB + tc*3 MB (xg now i16 fixed-point: 2MB/step + ohol 1MB/step)
// ---------------------------------------------------------------------------
static constexpr size_t SZ_WIM  = 4096ull * 512 * 2;   // W img  [4096][hi256|lo256]
static constexpr size_t SZ_FCW  = 1024ull * 2048 * 2;  // fc img [1024][hi1024|lo1024]
static constexpr size_t SZ_UIM  = 8388608;             // U i8 frag img, 2 planes
static constexpr size_t SZ_EBI  = 10000ull * 512 * 2;  // emb img [10000][hi256|lo256]
static constexpr size_t SZ_HH   = 33ull * 524288;      // h history [33 slot][256][1024] u16
static constexpr size_t SZ_CB   = 1048576;             // c state [256][1024] f32
static constexpr size_t SZ_LEN  = 4096;
static constexpr size_t SZ_DIAG = 2048;                // prog[0..15] + flags at +256B

DEVINL unsigned short bf16rn(float x){
  unsigned u = __float_as_uint(x);
  unsigned r = (u + 0x7fffu + ((u >> 16) & 1u)) >> 16;
  return (unsigned short)r;
}
DEVINL unsigned short bf16lo(float x){
  unsigned ub = __float_as_uint(x);
  return bf16rn(x - __uint_as_float(ub & 0xffff0000u));
}
DEVINL float sigm(float x){ return 1.f / (1.f + __expf(-x)); }
DEVINL float tanhfast(float x){
  float xc = fminf(15.f, fmaxf(-15.f, x));
  float e = __expf(2.f * xc);
  return (e - 1.f) / (e + 1.f);
}
// async 16B global->LDS DMA; LDS dest = wave-uniform base + lane*16,
// global source is PER-LANE (gather/pre-swizzle legal).  size must be literal.
DEVINL void gl_lds16(const void* g, void* l){
  __builtin_amdgcn_global_load_lds(
      (const __attribute__((address_space(1))) unsigned*)g,
      (__attribute__((address_space(3))) unsigned*)l, 16, 0, 0);
}
DEVINL int hslot(int t){ return t % 33; }   // 33 slots: distinct within a launch

// ---------------------------------------------------------------------------
__global__ void __launch_bounds__(256) probe_fill(float* __restrict__ out, int n, float v)
{
  int i = blockIdx.x * 256 + threadIdx.x;
  if (i < n) out[i] = (i == 0) ? v : 0.f;
}

// diag: if a stage marker is missing, flood out[0..1023] with 100+stage
__global__ void __launch_bounds__(64) diag_check(const int* __restrict__ prog,
                                                 float* __restrict__ out)
{
  if (threadIdx.x == 0){
    int miss = 0;
    for (int i = 7; i >= 1; i--) if (prog[i] == 0) miss = i;
    if (miss){
      for (int k = 0; k < 1024; k++) out[k] = 100.0f + (float)miss;
    }
  }
}

// ---------------------------------------------------------------------------
__global__ void __launch_bounds__(128) len_kernel(const int* __restrict__ seq,
                                                  int* __restrict__ len,
                                                  int* __restrict__ prog)
{
  int b = blockIdx.x, t = threadIdx.x;
  if (b == 0 && t == 0) prog[1] = 1;
  int pred = (seq[b * 128 + t] != 0) ? 1 : 0;
  unsigned long long m = __ballot(pred);
  __shared__ int cnt[2];
  if ((t & 63) == 0) cnt[t >> 6] = __popcll(m);
  __syncthreads();
  if (t == 0) len[b] = cnt[0] + cnt[1];
}

// ---------------------------------------------------------------------------
// transpose f32 [Ksrc][N] -> bf16 image [N][2*Ksrc] = [hi | lo]
// ---------------------------------------------------------------------------
__global__ void __launch_bounds__(256) prep_split_img(
    const float* __restrict__ S, unsigned short* __restrict__ img, int N, int Ksrc,
    int* __restrict__ prog, int stage)
{
  __shared__ float tile[64][65];
  const int nt = N >> 6;
  const int bn = blockIdx.x % nt, bk = blockIdx.x / nt;
  const int tid = threadIdx.x;
  if (blockIdx.x == 0 && tid == 0) prog[stage] = 1;
  {
    const int kk = tid >> 6, n = tid & 63;
#pragma unroll 4
    for (int i = 0; i < 16; i++){
      int k = i * 4 + kk;
      tile[k][n] = S[(size_t)((bk << 6) + k) * N + (bn << 6) + n];
    }
  }
  __syncthreads();
  {
    const int n4 = tid >> 6, k = tid & 63;
#pragma unroll 4
    for (int i = 0; i < 16; i++){
      int n = i * 4 + n4;
      float v = tile[k][n];
      size_t rowoff = (size_t)((bn << 6) + n) * (2 * Ksrc) + (bk << 6) + k;
      img[rowoff] = (unsigned short)(__float_as_uint(v) >> 16);
      img[rowoff + Ksrc] = bf16lo(v);
    }
  }
}

// ---------------------------------------------------------------------------
// emb f32 [10000][256] -> u16 image [10000][hi256|lo256]
// ---------------------------------------------------------------------------
__global__ void __launch_bounds__(256) prep_emb_img(const float* __restrict__ emb,
                                                    unsigned short* __restrict__ img)
{
  const int v = blockIdx.x, t = threadIdx.x;
  float x = emb[(size_t)v * 256 + t];
  img[(size_t)v * 512 + t]       = (unsigned short)(__float_as_uint(x) >> 16);
  img[(size_t)v * 512 + 256 + t] = bf16lo(x);
}

// ---------------------------------------------------------------------------
// U (f32 [1024][4096]) -> i8 fragment image, 2 planes (hi,lo of 16-bit *2^17)
// ---------------------------------------------------------------------------
__global__ void __launch_bounds__(256) prep_uimg(const float* __restrict__ U,
                                                 signed char* __restrict__ img,
                                                 int* __restrict__ prog)
{
  const int bid = blockIdx.x;
  const int nb = bid >> 2, nt4 = bid & 3;
  const int tid = threadIdx.x;
  if (bid == 0 && tid == 0) prog[4] = 1;
  __shared__ signed char lc[16384], ldq[16384];  // [k 1024][16 cols]
  const int colbase = nt4 * 1024 + (nb << 4);
  const int kk = tid >> 4, cc = tid & 15;
#pragma unroll 4
  for (int it = 0; it < 64; it++){
    int k = it * 16 + kk;
    float v = U[(size_t)k * 4096 + colbase + cc];
    int q = (int)rintf(v * 131072.f);            // U * 2^17
    q = q > 32639 ? 32639 : (q < -32639 ? -32639 : q);
    int a = (q + 128) >> 8;
    int d = q - (a << 8);
    lc[(k << 4) + cc]  = (signed char)a;
    ldq[(k << 4) + cc] = (signed char)d;
  }
  __syncthreads();
#pragma unroll
  for (int rep = 0; rep < 4; rep++){
    int idx = rep * 256 + tid;                   // 0..1023
    int kt = idx >> 6, lane = idx & 63;
    int n = lane & 15, quad = lane >> 4;
    union { signed char b[16]; i32x4 v; } cb_, db_;
#pragma unroll
    for (int j = 0; j < 16; j++){
      int k = (kt << 6) + (quad << 4) + j;
      cb_.b[j] = lc[(k << 4) + n];
      db_.b[j] = ldq[(k << 4) + n];
    }
    size_t base = (size_t)((((nb << 2) + nt4) * 16 + kt) * 2) * 1024;
    *(i32x4*)(img + base + (size_t)lane * 16)        = cb_.v;
    *(i32x4*)(img + base + 1024 + (size_t)lane * 16) = db_.v;
  }
}

// ---------------------------------------------------------------------------
// gates GEMM: xq[256*tc][4096] = i16 fixed-point round((emb x W + b)*2^14).
// R14: output quantized to i16 (halves the dominant xg HBM stream: 128->64MB
// write here + 64MB fetch in lstm).  |xg|max ~0.15 << 2.0 range; quant err
// 3e-5 << 7.2e-4 tolerance.  Double-buffered DMA pipeline (R12-proven).
// ---------------------------------------------------------------------------
__global__ void __launch_bounds__(256) gemm_gates(
    const unsigned short* __restrict__ Aimg, const unsigned short* __restrict__ Bimg,
    const float* __restrict__ bias, unsigned short* __restrict__ D,
    const int* __restrict__ seq, int c0, int tcsh, int* __restrict__ prog)
{
  __shared__ __align__(16) char lds[32768];
  __shared__ int stok[128];
  const int tid = threadIdx.x, lane = tid & 63, wv = tid >> 6;
  const int quad = lane >> 4, nlo = lane & 15;
  const int wm = wv & 1, wn = wv >> 1;
  const int rowbase = (blockIdx.x >> 5) << 7;   // 32 col-tiles
  const int colbase = (blockIdx.x & 31) << 7;
  const int tcm1 = (1 << tcsh) - 1;
  if (blockIdx.x == 0 && tid == 0) prog[5] = 1;
  if (tid < 128){
    int r = rowbase + tid;
    stok[tid] = seq[((r >> tcsh) << 7) + c0 + (r & tcm1)];
  }
  __syncthreads();

  f32x4 acc[4][4];
#pragma unroll
  for (int i = 0; i < 4; i++)
#pragma unroll
    for (int j = 0; j < 4; j++) acc[i][j] = (f32x4){0.f, 0.f, 0.f, 0.f};

  const unsigned short* asrc[2]; const unsigned short* bsrc[2];
  char* adst[2]; char* bdst[2];
#pragma unroll
  for (int p = 0; p < 2; p++){
    int gidx = p * 256 + tid;
    int row = gidx >> 2, sg = gidx & 3;
    int sgs = sg ^ ((row >> 1) & 3);
    asrc[p] = Aimg + (size_t)stok[row] * 512 + sgs * 8;
    bsrc[p] = Bimg + (size_t)(colbase + row) * 512 + sgs * 8;
    adst[p] = &lds[p * 4096 + wv * 1024];
    bdst[p] = &lds[16384 + p * 4096 + wv * 1024];
  }

  auto stage = [&](int c, int cur){
    int k0 = c * 32;
    int seg = (k0 >= 512) ? 2 : (k0 >= 256 ? 1 : 0);
    int acol = k0 - seg * 256;
    int aoff = (seg == 1 ? 256 : 0) + acol;
    int boff = (seg == 2 ? 256 : 0) + acol;
#pragma unroll
    for (int p = 0; p < 2; p++){
      gl_lds16(asrc[p] + aoff, adst[p] + cur * 8192);
      gl_lds16(bsrc[p] + boff, bdst[p] + cur * 8192);
    }
  };

  stage(0, 0);
  int cur = 0;
#pragma unroll 2
  for (int c = 0; c < 24; c++){
    __syncthreads();                     // buf[cur] DMA complete on all waves
    if (c + 1 < 24) stage(c + 1, cur ^ 1);
    bf16x8 af[4], bfr[4];
#pragma unroll
    for (int mt = 0; mt < 4; mt++){
      int r = wm * 64 + mt * 16 + nlo;
      af[mt] = *(const bf16x8*)(&lds[cur * 8192 + r * 64 + ((quad ^ ((r >> 1) & 3)) << 4)]);
    }
#pragma unroll
    for (int nt = 0; nt < 4; nt++){
      int r = wn * 64 + nt * 16 + nlo;
      bfr[nt] = *(const bf16x8*)(&lds[16384 + cur * 8192 + r * 64 + ((quad ^ ((r >> 1) & 3)) << 4)]);
    }
#pragma unroll
    for (int mt = 0; mt < 4; mt++)
#pragma unroll
      for (int nt = 0; nt < 4; nt++)
        acc[mt][nt] = __builtin_amdgcn_mfma_f32_16x16x32_bf16(af[mt], bfr[nt], acc[mt][nt], 0, 0, 0);
    cur ^= 1;
  }

  float bs[4];
#pragma unroll
  for (int nt = 0; nt < 4; nt++) bs[nt] = bias[colbase + wn * 64 + nt * 16 + nlo];
#pragma unroll
  for (int mt = 0; mt < 4; mt++)
#pragma unroll
    for (int nt = 0; nt < 4; nt++){
      int col = colbase + wn * 64 + nt * 16 + nlo;
#pragma unroll
      for (int r = 0; r < 4; r++){
        int row = rowbase + wm * 64 + mt * 16 + quad * 4 + r;
        float v = acc[mt][nt][r] + bs[nt];
        int q = (int)rintf(v * 16384.f);
        q = q > 32767 ? 32767 : (q < -32767 ? -32767 : q);
        D[(size_t)row * 4096 + col] = (unsigned short)(short)q;
      }
    }
}

// ---------------------------------------------------------------------------
// output GEMM: out[b*128+c0+s][1024] = ohol x fcw + fcb (3-product, K'=3072)
// Double-buffered DMA pipeline (R12).
// ---------------------------------------------------------------------------
__global__ void __launch_bounds__(256) gemm_out(
    const unsigned short* __restrict__ ohol, const unsigned short* __restrict__ Bimg,
    const float* __restrict__ bias, float* __restrict__ D,
    int c0, int tcsh, int* __restrict__ prog)
{
  __shared__ __align__(16) char lds[32768];
  const int tid = threadIdx.x, lane = tid & 63, wv = tid >> 6;
  const int quad = lane >> 4, nlo = lane & 15;
  const int wm = wv & 1, wn = wv >> 1;
  const int rowbase = (blockIdx.x >> 3) << 7;   // 8 col-tiles
  const int colbase = (blockIdx.x & 7) << 7;
  const int tcm1 = (1 << tcsh) - 1;
  if (blockIdx.x == 0 && tid == 0) prog[7] = 1;

  f32x4 acc[4][4];
#pragma unroll
  for (int i = 0; i < 4; i++)
#pragma unroll
    for (int j = 0; j < 4; j++) acc[i][j] = (f32x4){0.f, 0.f, 0.f, 0.f};

  const unsigned short* asrc[2]; const unsigned short* bsrc[2];
  char* adst[2]; char* bdst[2];
#pragma unroll
  for (int p = 0; p < 2; p++){
    int gidx = p * 256 + tid;
    int row = gidx >> 2, sg = gidx & 3;
    int sgs = sg ^ ((row >> 1) & 3);
    asrc[p] = ohol + (size_t)(rowbase + row) * 2048 + sgs * 8;
    bsrc[p] = Bimg + (size_t)(colbase + row) * 2048 + sgs * 8;
    adst[p] = &lds[p * 4096 + wv * 1024];
    bdst[p] = &lds[16384 + p * 4096 + wv * 1024];
  }

  auto stage = [&](int c, int cur){
    int k0 = c * 32;
    int seg = (k0 >= 2048) ? 2 : (k0 >= 1024 ? 1 : 0);
    int acol = k0 - seg * 1024;
    int aoff = (seg == 1 ? 1024 : 0) + acol;
    int boff = (seg == 2 ? 1024 : 0) + acol;
#pragma unroll
    for (int p = 0; p < 2; p++){
      gl_lds16(asrc[p] + aoff, adst[p] + cur * 8192);
      gl_lds16(bsrc[p] + boff, bdst[p] + cur * 8192);
    }
  };

  stage(0, 0);
  int cur = 0;
#pragma unroll 2
  for (int c = 0; c < 96; c++){
    __syncthreads();                     // buf[cur] DMA complete on all waves
    if (c + 1 < 96) stage(c + 1, cur ^ 1);
    bf16x8 af[4], bfr[4];
#pragma unroll
    for (int mt = 0; mt < 4; mt++){
      int r = wm * 64 + mt * 16 + nlo;
      af[mt] = *(const bf16x8*)(&lds[cur * 8192 + r * 64 + ((quad ^ ((r >> 1) & 3)) << 4)]);
    }
#pragma unroll
    for (int nt = 0; nt < 4; nt++){
      int r = wn * 64 + nt * 16 + nlo;
      bfr[nt] = *(const bf16x8*)(&lds[16384 + cur * 8192 + r * 64 + ((quad ^ ((r >> 1) & 3)) << 4)]);
    }
#pragma unroll
    for (int mt = 0; mt < 4; mt++)
#pragma unroll
      for (int nt = 0; nt < 4; nt++)
        acc[mt][nt] = __builtin_amdgcn_mfma_f32_16x16x32_bf16(af[mt], bfr[nt], acc[mt][nt], 0, 0, 0);
    cur ^= 1;
  }

  float bs[4];
#pragma unroll
  for (int nt = 0; nt < 4; nt++) bs[nt] = bias[colbase + wn * 64 + nt * 16 + nlo];
#pragma unroll
  for (int mt = 0; mt < 4; mt++)
#pragma unroll
    for (int nt = 0; nt < 4; nt++){
      int col = colbase + wn * 64 + nt * 16 + nlo;
#pragma unroll
      for (int r = 0; r < 4; r++){
        int row = rowbase + wm * 64 + mt * 16 + quad * 4 + r;
        int drow = ((row >> tcsh) << 7) + c0 + (row & tcm1);
        D[(size_t)drow * 1024 + col] = acc[mt][nt][r] + bs[nt];
      }
    }
}

// ---------------------------------------------------------------------------
// per-mb-group FLAG-ARRAY barrier (64 WGs), ZERO cache maintenance (R9-proven;
// R13's per-chunk dataflow variant REGRESSED -> reverted to this):
//   Writer: h(t+1) via RETURNING agent-scope 32-bit atomic_exchange (result
//   consumed) -> executes at the MALL; vmcnt retires on response -> after
//   __syncthreads() all h-words are AT the coherence point.
//   Reader: h addresses are LAUNCH-FRESH (hh slot history, 33 distinct slots
//   per launch) -> no stale copies possible -> plain cached loads, NO fence.
//   - wait: wave 0 polls all 64 flags IN PARALLEL (lane i -> flag[i]).
//   - workgroup acquire fence = compiler-only ordering (no cache ops).
// ---------------------------------------------------------------------------
DEVINL void mbbar(int* flags, int nb, int t, int wv, int lane){
  __syncthreads();   // vmcnt(0) per wave: all h-exchanges RESPONDED (at MALL)
  if (wv == 0){
    if (lane == 0)
      __hip_atomic_store(&flags[nb], t + 1, __ATOMIC_RELAXED, __HIP_MEMORY_SCOPE_AGENT);
    const int tgt = t + 1;
    for (;;){
      int v = __hip_atomic_load(&flags[lane], __ATOMIC_RELAXED, __HIP_MEMORY_SCOPE_AGENT);
      if (__ballot(v >= tgt) == ~0ull) break;
      __builtin_amdgcn_s_sleep(1);
    }
    __builtin_amdgcn_fence(__ATOMIC_ACQUIRE, "workgroup");  // compiler ordering only
  }
  __syncthreads();
}

// ---------------------------------------------------------------------------
// persistent LSTM recurrence, tc steps/launch.  256 WGs x 512 thr = 4 mb x 64 nb.
// R14: R12-proven body; xg input is now i16 fixed-point (xq * 2^-14).  Each
// thread loads ONE int4 (8 u16, 16B) per step and converts to f32 at the
// LDS-fill point; LDS layout and elementwise code unchanged.
// ---------------------------------------------------------------------------
__global__ void __launch_bounds__(512, 2) lstm_rec(
    const unsigned short* __restrict__ xq, // [256*tc][4096] i16, row = b*tc+s
    const signed char* __restrict__ uimg,
    const int* __restrict__ len,
    signed char* __restrict__ hh,        // [33 slot][256][1024] u16 packed history
    float* __restrict__ cbuf,            // [256][1024] f32
    unsigned short* __restrict__ ohol,   // [256*tc][hi1024|lo1024]
    int* __restrict__ barbase,           // flags[mb] at barbase + mb*64 ints
    int* __restrict__ prog,
    int c0, int tcsh)
{
  // LDS: [0,16384) h tile (2 pl x 64 r x 128B, 16B-granule XOR swizzle);
  //      [16384,32768) xg f32 [64][64]; [32768,50176) z f32 [64][68]
  __shared__ __align__(16) char lds[50176];
  const int tc = 1 << tcsh;
  const int wg = blockIdx.x, mb = wg >> 6, nb = wg & 63;
  const int tid = threadIdx.x, lane = tid & 63, wv = tid >> 6;  // wv 0..7
  const int quad = lane >> 4, nlo = lane & 15;
  const int mh = wv & 1, g = wv >> 1;                           // gate 0..3
  int* flags = barbase + (mb << 6);
  if (wg == 0 && tid == 0) prog[6] = 1;

  const unsigned short* hh2 = (const unsigned short*)hh;

  // ---- U fragments -> registers: gate g, u-block nb, 16 kt x 2 planes ----
  i32x4 Bf[16][2];
#pragma unroll
  for (int kt = 0; kt < 16; kt++)
#pragma unroll
    for (int pl = 0; pl < 2; pl++){
      size_t off = (size_t)((((nb << 2) + g) * 16 + kt) * 2 + pl);
      off = (off * 64 + lane) << 4;
      Bf[kt][pl] = *(const i32x4*)(uimg + off);
    }

  // ---- elementwise mapping: thread = (1 row x 2 adjacent cols) ----
  const int erow = tid >> 3;            // 0..63 local row
  const int ecp  = tid & 7;             // col-pair index
  const int ecol0 = ecp << 1;           // local col (even)
  const int ucol0 = (nb << 4) + ecol0;  // global u col (even)
  const int bglob = (mb << 6) + erow;
  const int lenr = len[bglob];
  float cst[2], hst[2];
#pragma unroll
  for (int r = 0; r < 2; r++){
    cst[r] = cbuf[(size_t)bglob * 1024 + ucol0 + r];
    unsigned short e = hh2[(size_t)hslot(c0) * 262144 + (size_t)bglob * 1024 + ucol0 + r];
    int a = (signed char)(e >> 8), b_ = (signed char)(e & 255);
    hst[r] = (float)(a * 256 + b_) * (1.0f / 32512.0f);
  }

  // xq prefetch: one int4 (8 u16) per thread; row = tid>>3,
  // gate = (tid&7)>>1, half = tid&1 -> cols gate*16+half*8 .. +8 of this nb.
  const int xrow = tid >> 3, xgt = (tid & 7) >> 1, xhf = tid & 1;
  int4 xreg;
  auto load_x = [&](int s){
    size_t grow = (size_t)((((mb << 6) + xrow) << tcsh) + s);
    xreg = *(const int4*)(xq + grow * 4096 + (xgt << 10) + (nb << 4) + (xhf << 3));
  };
  load_x(0);

  // h staging mapping: thread = (1 row x one 32B packed block of 8)
  const int hrw = tid >> 3, hsub = tid & 7;

#pragma unroll 1
  for (int s = 0; s < tc; s++){
    const int t = c0 + s;
    // input h of step t lives at slot hslot(t) (launch-fresh -> plain loads)
    const signed char* hsrc = hh + (size_t)hslot(t) * 524288 + (size_t)(mb << 6) * 2048;

    i32x4 accH[2], accM[2], accL[2];
#pragma unroll
    for (int m = 0; m < 2; m++){
      accH[m] = (i32x4){0,0,0,0};
      accM[m] = (i32x4){0,0,0,0};
      accL[m] = (i32x4){0,0,0,0};
    }

    int4 hregA[2], hregB[2];
    auto load_hto = [&](int c, int4* dst){
      const signed char* p = hsrc + (size_t)hrw * 2048 + c * 256 + hsub * 32;
      dst[0] = *(const int4*)p;
      dst[1] = *(const int4*)(p + 16);
    };
    // split packed u16 block (16 cols) -> hi plane 16B + lo plane 16B, write
    // with the R5 16B-granule swizzle (low bank-conflict layout).
    auto write_hf = [&](const int4* src){
      unsigned r0 = (unsigned)src[0].x, r1 = (unsigned)src[0].y;
      unsigned r2 = (unsigned)src[0].z, r3 = (unsigned)src[0].w;
      unsigned r4 = (unsigned)src[1].x, r5 = (unsigned)src[1].y;
      unsigned r6 = (unsigned)src[1].z, r7 = (unsigned)src[1].w;
      i32x4 lo, hi;
      lo[0] = __builtin_amdgcn_perm(r1, r0, 0x06040200u);
      lo[1] = __builtin_amdgcn_perm(r3, r2, 0x06040200u);
      lo[2] = __builtin_amdgcn_perm(r5, r4, 0x06040200u);
      lo[3] = __builtin_amdgcn_perm(r7, r6, 0x06040200u);
      hi[0] = __builtin_amdgcn_perm(r1, r0, 0x07050301u);
      hi[1] = __builtin_amdgcn_perm(r3, r2, 0x07050301u);
      hi[2] = __builtin_amdgcn_perm(r5, r4, 0x07050301u);
      hi[3] = __builtin_amdgcn_perm(r7, r6, 0x07050301u);
      int sw = (hsub ^ (hrw & 7)) << 4;
      *(i32x4*)(&lds[hrw * 128 + sw])        = hi;   // plane 0 = hi bytes (a)
      *(i32x4*)(&lds[8192 + hrw * 128 + sw]) = lo;   // plane 1 = lo bytes (b)
    };

    load_hto(0, hregA);
    load_hto(1, hregB);

#pragma unroll                         // FULL unroll: Bf[kt] compile-time
    for (int c = 0; c < 8; c++){
      __syncthreads();
      if ((c & 1) == 0) write_hf(hregA); else write_hf(hregB);
      if (c == 0){
        // convert 8 i16 -> 8 f32 and fill the xg LDS tile (layout unchanged)
        union { int4 v; unsigned short u[8]; } xu; xu.v = xreg;
        const float xs = 1.0f / 16384.f;
        float4 f0, f1;
        f0.x = (float)(short)xu.u[0] * xs; f0.y = (float)(short)xu.u[1] * xs;
        f0.z = (float)(short)xu.u[2] * xs; f0.w = (float)(short)xu.u[3] * xs;
        f1.x = (float)(short)xu.u[4] * xs; f1.y = (float)(short)xu.u[5] * xs;
        f1.z = (float)(short)xu.u[6] * xs; f1.w = (float)(short)xu.u[7] * xs;
        char* xb = &lds[16384 + xrow * 256 + (((xgt << 4) + (xhf << 3)) << 2)];
        *(float4*)xb = f0;
        *(float4*)(xb + 16) = f1;
      }
      __syncthreads();
      if (c + 2 < 8){
        if ((c & 1) == 0) load_hto(c + 2, hregA); else load_hto(c + 2, hregB);
      }
#pragma unroll
      for (int kt2 = 0; kt2 < 2; kt2++){
        const int kt = c * 2 + kt2;
        i32x4 Af[2][2];
#pragma unroll
        for (int m = 0; m < 2; m++){
          int hrow = (mh << 5) + (m << 4) + nlo;
          int sgl = ((kt2 << 2) + quad) ^ (hrow & 7);
          Af[m][0] = *(const i32x4*)(&lds[hrow * 128 + (sgl << 4)]);
          Af[m][1] = *(const i32x4*)(&lds[8192 + hrow * 128 + (sgl << 4)]);
        }
#pragma unroll
        for (int m = 0; m < 2; m++){
          accH[m] = __builtin_amdgcn_mfma_i32_16x16x64_i8(Af[m][0], Bf[kt][0], accH[m], 0, 0, 0);
          accM[m] = __builtin_amdgcn_mfma_i32_16x16x64_i8(Af[m][0], Bf[kt][1], accM[m], 0, 0, 0);
          accM[m] = __builtin_amdgcn_mfma_i32_16x16x64_i8(Af[m][1], Bf[kt][0], accM[m], 0, 0, 0);
          accL[m] = __builtin_amdgcn_mfma_i32_16x16x64_i8(Af[m][1], Bf[kt][1], accL[m], 0, 0, 0);
        }
      }
    }
    __syncthreads();

    // prefetch next step's xq under the z/elementwise/barrier phases
    if (s + 1 < tc) load_x(s + 1);

    // ---- z = (65536*accH + 256*accM + accL)/(32512*2^17) -> LDS ----
    const float cH = 1.0f / 65024.0f;
    const float cM = 1.0f / 16646144.0f;
    const float cL = 1.0f / 4261412864.0f;
#pragma unroll
    for (int m = 0; m < 2; m++){
#pragma unroll
      for (int r = 0; r < 4; r++){
        float z = (float)accH[m][r] * cH
                + (float)accM[m][r] * cM
                + (float)accL[m][r] * cL;
        int zrow = (mh << 5) + (m << 4) + (quad << 2) + r;
        *(float*)(&lds[32768 + (((zrow * 68) + g * 16 + nlo) << 2)]) = z;
      }
    }
    __syncthreads();

    {
      float ho16[2];
      unsigned enc2 = 0;
#pragma unroll
      for (int r = 0; r < 2; r++){
        int col = ecol0 + r;
        float zi = *(const float*)(&lds[32768 + (((erow * 68) + 0  + col) << 2)])
                 + *(const float*)(&lds[16384 + (((erow << 6) + 0  + col) << 2)]);
        float zf = *(const float*)(&lds[32768 + (((erow * 68) + 16 + col) << 2)])
                 + *(const float*)(&lds[16384 + (((erow << 6) + 16 + col) << 2)]);
        float zg = *(const float*)(&lds[32768 + (((erow * 68) + 32 + col) << 2)])
                 + *(const float*)(&lds[16384 + (((erow << 6) + 32 + col) << 2)]);
        float zo = *(const float*)(&lds[32768 + (((erow * 68) + 48 + col) << 2)])
                 + *(const float*)(&lds[16384 + (((erow << 6) + 48 + col) << 2)]);
        float iv = sigm(zi), fv = sigm(zf), ov = sigm(zo), gv = tanhfast(zg);
        float cn = fv * cst[r] + iv * gv;
        float hn = ov * tanhfast(cn);
        bool vld = (t < lenr);
        cst[r] = vld ? cn : cst[r];
        hst[r] = vld ? hn : hst[r];
        ho16[r] = vld ? hn : 0.f;
        int H = (int)rintf(hst[r] * 32512.f);
        H = H > 32512 ? 32512 : (H < -32512 ? -32512 : H);
        int a = (H + 128) >> 8;
        int b_ = H - (a << 8);
        unsigned e = (((unsigned)a & 255u) << 8) | ((unsigned)b_ & 255u);
        enc2 |= e << (r * 16);
      }
      // ohol: 2 adjacent cols -> u32 stores (hi plane, lo plane)
      size_t orow = ((size_t)bglob << tcsh) + s;
      unsigned hi2 = (unsigned)(__float_as_uint(ho16[0]) >> 16)
                   | ((unsigned)(__float_as_uint(ho16[1]) >> 16) << 16);
      unsigned lo2 = (unsigned)bf16lo(ho16[0]) | ((unsigned)bf16lo(ho16[1]) << 16);
      *(unsigned*)(ohol + orow * 2048 + ucol0)        = hi2;
      *(unsigned*)(ohol + orow * 2048 + 1024 + ucol0) = lo2;
      // h(t+1) -> FRESH slot: ONE returning 32-bit atomic exchange (provable
      // release — vmcnt retires only on MALL response; see mbbar).
      unsigned* hp = (unsigned*)(hh + (size_t)hslot(t + 1) * 524288
                                 + ((size_t)bglob * 1024 + ucol0) * 2);
      unsigned old = __hip_atomic_exchange(hp, enc2, __ATOMIC_RELAXED,
                                           __HIP_MEMORY_SCOPE_AGENT);
      asm volatile("" :: "v"(old));   // consume result -> returning form
    }
    mbbar(flags, nb, t, wv, lane);
  }

#pragma unroll
  for (int r = 0; r < 2; r++)
    cbuf[(size_t)bglob * 1024 + ucol0 + r] = cst[r];
}

// ---------------------------------------------------------------------------
extern "C" void kernel_launch(void* const* d_in, const int* in_sizes, int n_in,
                              void* d_out, int out_size, void* d_ws, size_t ws_size,
                              hipStream_t stream)
{
  const int*   seq = (const int*)  d_in[0];
  const float* emb = (const float*)d_in[1];
  const float* Wm  = (const float*)d_in[2];
  const float* Um  = (const float*)d_in[3];
  const float* bv  = (const float*)d_in[4];
  const float* fcW = (const float*)d_in[5];
  const float* fcb = (const float*)d_in[6];
  float* out = (float*)d_out;
  char* ws = (char*)d_ws;

  // marker: survives iff no kernel/memset below ever touches d_out
  hipMemsetAsync(d_out, 0x42, 256, stream);   // 64 floats = 48.566

  size_t off = 0;
  unsigned short* wim = (unsigned short*)(ws + off); off += SZ_WIM;
  unsigned short* fcw = (unsigned short*)(ws + off); off += SZ_FCW;
  signed char*    uim = (signed char*)(ws + off);    off += SZ_UIM;
  unsigned short* ebi = (unsigned short*)(ws + off); off += SZ_EBI;
  signed char*    hh  = (signed char*)(ws + off);    off += SZ_HH;
  float*          cb  = (float*)(ws + off);          off += SZ_CB;
  int*            len = (int*)(ws + off);            off += SZ_LEN;
  int*            diag= (int*)(ws + off);            off += SZ_DIAG;
  const size_t fixed = off;

  // per-chunk buffers: xq (tc*2MB, i16) + ohol (tc*1MB) = 3MB * tc
  int tcsh = -1;
  for (int s = 5; s >= 0; s--)
    if (ws && fixed + (3145728ull << s) <= ws_size){ tcsh = s; break; }

  if (tcsh < 0){
    probe_fill<<<(out_size + 255) / 256, 256, 0, stream>>>(
        out, out_size, 1000.0f + (float)(ws_size >> 20));
    return;
  }
  const int tc = 1 << tcsh;

  unsigned short* xqc  = (unsigned short*)(ws + fixed);
  unsigned short* ohol = (unsigned short*)(ws + fixed + (size_t)tc * 2097152);

  hipMemsetAsync(diag, 0, SZ_DIAG, stream);   // prog + per-mb barrier flags
  hipMemsetAsync(hh, 0, 524288, stream);      // h history slot 0 = 0 (enc(0)=0)
  hipMemsetAsync(cb, 0, SZ_CB, stream);       // c state = 0

  int* prog = diag;
  int* barbase = diag + 64;                   // flags: 4 mb x 64 ints, 256B apart

  len_kernel<<<256, 128, 0, stream>>>(seq, len, prog);
  prep_split_img<<<256, 256, 0, stream>>>(Wm, wim, 4096, 256, prog, 2);
  prep_split_img<<<256, 256, 0, stream>>>(fcW, fcw, 1024, 1024, prog, 3);
  prep_emb_img<<<10000, 256, 0, stream>>>(emb, ebi);
  prep_uimg<<<256, 256, 0, stream>>>(Um, uim, prog);

  for (int c0 = 0; c0 < 128; c0 += tc){
    gemm_gates<<<dim3((2 * tc) * 32), 256, 0, stream>>>(ebi, wim, bv, xqc, seq, c0, tcsh, prog);
    lstm_rec<<<dim3(256), 512, 0, stream>>>(xqc, uim, len, hh, cb, ohol, barbase, prog, c0, tcsh);
    gemm_out<<<dim3((2 * tc) * 8), 256, 0, stream>>>(ohol, fcw, fcb, out, c0, tcsh, prog);
  }

  diag_check<<<1, 64, 0, stream>>>(prog, out);
}